// Round 1
// 804.521 us; speedup vs baseline: 1.8359x; 1.8359x over previous
//
#include <hip/hip_runtime.h>
#include <math.h>

#define BB 8
#define CC 256
#define HH 224
#define WW 224
#define HWSZ (HH * WW)
#define HW2  (HWSZ / 2)
#define C4 64

__device__ __forceinline__ float sigmoidf_(float z) {
    return 1.0f / (1.0f + __expf(-z));
}

// ---------------------------------------------------------------------------
// K1: one full pass over x.
//  - per-pixel spatial logit accumulated in registers (thread = 1 float2).
//  - per-(b,c) sum over HW via LDS transpose: wave writes per-pixel partials
//    into a [32ch][64lane] tile, re-reads transposed (lane = channel),
//    sums in registers. No per-channel shuffle chains, no per-channel
//    global atomics. One coalesced global atomic per channel per block.
// grid (98, B), block 256 (4 waves). LDS 34.3 KB.
// ---------------------------------------------------------------------------
__global__ __launch_bounds__(256) void k1_spatial_avg(
    const float* __restrict__ x, const float* __restrict__ sw,
    const float* __restrict__ sb, float* __restrict__ spatial_sig,
    float* __restrict__ avgsum)
{
    __shared__ float tile[4][32][65];   // per-wave transpose tile, padded
    __shared__ float chansum[CC];
    const int tid  = threadIdx.x;
    const int wave = tid >> 6;
    const int lane = tid & 63;
    const int b    = blockIdx.y;
    const int p2   = blockIdx.x * 256 + tid;       // float2 index in [0, HW/2)
    const float2* xp = (const float2*)(x + (size_t)b * CC * HWSZ) + p2;

    chansum[tid] = 0.f;
    __syncthreads();

    float s0 = 0.f, s1 = 0.f;
    #pragma unroll 1
    for (int ct = 0; ct < 8; ++ct) {               // 8 tiles of 32 channels
        #pragma unroll
        for (int jj = 0; jj < 4; ++jj) {           // 4 batches of 8 loads
            float2 v[8];
            #pragma unroll
            for (int u = 0; u < 8; ++u)
                v[u] = xp[(size_t)(ct * 32 + jj * 8 + u) * HW2];
            #pragma unroll
            for (int u = 0; u < 8; ++u) {
                const int c = ct * 32 + jj * 8 + u;
                const float w = sw[c];             // uniform -> scalar load
                s0 = fmaf(v[u].x, w, s0);
                s1 = fmaf(v[u].y, w, s1);
                tile[wave][jj * 8 + u][lane] = v[u].x + v[u].y;
            }
        }
        __syncthreads();
        // transposed read: lane -> channel, 2-way bank aliasing only (free)
        const int cl  = lane & 31;
        const int seg = lane >> 5;
        float part = 0.f;
        #pragma unroll 8
        for (int j = 0; j < 32; ++j)
            part += tile[wave][cl][seg * 32 + j];
        part += __shfl_xor(part, 32, 64);          // combine seg 0/1
        if (lane < 32) atomicAdd(&chansum[ct * 32 + cl], part);  // LDS atomic
        __syncthreads();
    }

    const float bias = sb[0];
    float2 o;
    o.x = sigmoidf_(s0 + bias);
    o.y = sigmoidf_(s1 + bias);
    ((float2*)(spatial_sig + (size_t)b * HWSZ))[p2] = o;

    __syncthreads();
    // one coalesced global atomic per channel per block
    atomicAdd(&avgsum[b * CC + tid], chansum[tid]);
}

// ---------------------------------------------------------------------------
// K2: channel MLP. grid (B), block 64. (unchanged — negligible cost)
// ---------------------------------------------------------------------------
__global__ __launch_bounds__(64) void k2_channel(
    const float* __restrict__ avgsum, const float* __restrict__ w1,
    const float* __restrict__ b1, const float* __restrict__ w2,
    const float* __restrict__ b2, float* __restrict__ channel_sig)
{
    __shared__ float avg[CC];
    __shared__ float hsh[C4];
    const int b = blockIdx.x;
    const int t = threadIdx.x;
    const float inv = 1.0f / (float)HWSZ;
    for (int c = t; c < CC; c += 64) avg[c] = avgsum[b * CC + c] * inv;
    __syncthreads();

    float acc = b1[t];
    const float* wrow = w1 + t * CC;     // cc1_w is (64, 256) row-major
    #pragma unroll 4
    for (int c = 0; c < CC; ++c) acc = fmaf(avg[c], wrow[c], acc);
    hsh[t] = fmaxf(acc, 0.f);
    __syncthreads();

    for (int c = t; c < CC; c += 64) {
        float a = b2[c];
        const float* w2r = w2 + c * C4;  // cc2_w is (256, 64) row-major
        #pragma unroll
        for (int o = 0; o < C4; ++o) a = fmaf(hsh[o], w2r[o], a);
        channel_sig[b * CC + c] = sigmoidf_(a);
    }
}

// ---------------------------------------------------------------------------
// K3: rolling-register row stencil. One wave streams a 28-row strip of one
// (b,c) plane; lane q owns float4 column q (q<56). Per row: 1 x load +
// 1 spatial load + 1 store (3 VMEM vs 11 before); horizontal halos via
// 2 in-wave shuffles; vertical reuse in registers; x prefetched 2 rows
// ahead, spatial 1 row ahead.
// grid (2, B*C), block (64, 4): strip = blockIdx.x*4 + threadIdx.y.
// ---------------------------------------------------------------------------
__device__ __forceinline__ float4 horiz4(float4 v, int q) {
    float l  = __shfl(v.w, q - 1, 64);
    float rr = __shfl(v.x, q + 1, 64);
    l  = (q == 0)  ? 0.f : l;    // zero padding at col -1
    rr = (q == 55) ? 0.f : rr;   // zero padding at col 224
    float4 h;
    h.x = l   + v.x + v.y;
    h.y = v.x + v.y + v.z;
    h.z = v.y + v.z + v.w;
    h.w = v.z + v.w + rr;
    return h;
}

__global__ __launch_bounds__(256) void k3_out(
    const float* __restrict__ x, const float* __restrict__ spatial_sig,
    const float* __restrict__ channel_sig, float* __restrict__ out)
{
    const int bc = blockIdx.y;               // b*C + c
    const int b  = bc >> 8;
    const int strip = blockIdx.x * 4 + threadIdx.y;  // 0..7, 28 rows each
    const int q  = threadIdx.x;              // lane = float4 column
    if (q >= 56) return;                     // 224/4 = 56 columns
    const int r0   = strip * 28;
    const int col0 = q * 4;

    const float* plane    = x           + (size_t)bc * HWSZ;
    const float* sp_plane = spatial_sig + (size_t)b  * HWSZ;
    float*       o_plane  = out         + (size_t)bc * HWSZ;
    const float  ch = channel_sig[bc];

    const float4 z4 = make_float4(0.f, 0.f, 0.f, 0.f);
    // prime the pipeline: rows r0-1 .. r0+2  (r0+2 <= 198 < 224 always)
    float4 vm = (r0 > 0) ? *(const float4*)(plane + (r0 - 1) * WW + col0) : z4;
    float4 vc = *(const float4*)(plane + (r0    ) * WW + col0);
    float4 vp = *(const float4*)(plane + (r0 + 1) * WW + col0);
    float4 vn = *(const float4*)(plane + (r0 + 2) * WW + col0);
    float4 sp = *(const float4*)(sp_plane + r0 * WW + col0);

    float4 hs_m = horiz4(vm, q);
    float4 hs_c = horiz4(vc, q);

    #pragma unroll 4
    for (int r = r0; r < r0 + 28; ++r) {
        // prefetch x row r+3 (2 iterations ahead of use)
        float4 vq = (r + 3 < HH)
                  ? *(const float4*)(plane + (r + 3) * WW + col0) : z4;
        // prefetch spatial row r+1 (1 iteration ahead)
        float4 sp_n = (r + 1 < HH)
                  ? *(const float4*)(sp_plane + (r + 1) * WW + col0) : z4;
        float4 hs_p = horiz4(vp, q);

        float4 o;
        o.x = vc.x * sp.x * ch * sigmoidf_(9.f * vc.x - (hs_m.x + hs_c.x + hs_p.x));
        o.y = vc.y * sp.y * ch * sigmoidf_(9.f * vc.y - (hs_m.y + hs_c.y + hs_p.y));
        o.z = vc.z * sp.z * ch * sigmoidf_(9.f * vc.z - (hs_m.z + hs_c.z + hs_p.z));
        o.w = vc.w * sp.w * ch * sigmoidf_(9.f * vc.w - (hs_m.w + hs_c.w + hs_p.w));
        *(float4*)(o_plane + r * WW + col0) = o;

        vc = vp; vp = vn; vn = vq;
        hs_m = hs_c; hs_c = hs_p;
        sp = sp_n;
    }
}

// ---------------------------------------------------------------------------
extern "C" void kernel_launch(void* const* d_in, const int* in_sizes, int n_in,
                              void* d_out, int out_size, void* d_ws, size_t ws_size,
                              hipStream_t stream) {
    const float* x  = (const float*)d_in[0];
    const float* sw = (const float*)d_in[1];
    const float* sb = (const float*)d_in[2];
    const float* w1 = (const float*)d_in[3];
    const float* b1 = (const float*)d_in[4];
    const float* w2 = (const float*)d_in[5];
    const float* b2 = (const float*)d_in[6];
    float* out = (float*)d_out;

    float* spatial_sig = (float*)d_ws;                       // B*HW floats
    float* avgsum      = spatial_sig + (size_t)BB * HWSZ;    // B*C floats
    float* channel_sig = avgsum + BB * CC;                   // B*C floats

    hipMemsetAsync(avgsum, 0, BB * CC * sizeof(float), stream);

    k1_spatial_avg<<<dim3(HWSZ / 512, BB), 256, 0, stream>>>(
        x, sw, sb, spatial_sig, avgsum);
    k2_channel<<<dim3(BB), 64, 0, stream>>>(
        avgsum, w1, b1, w2, b2, channel_sig);
    k3_out<<<dim3(2, BB * CC), dim3(64, 4), 0, stream>>>(
        x, spatial_sig, channel_sig, out);
}

// Round 2
// 787.474 us; speedup vs baseline: 1.8756x; 1.0216x over previous
//
#include <hip/hip_runtime.h>
#include <math.h>

#define BB 8
#define CC 256
#define HH 224
#define WW 224
#define HWSZ (HH * WW)
#define HW2  (HWSZ / 2)
#define C4 64

typedef float f4 __attribute__((ext_vector_type(4)));

__device__ __forceinline__ float sigmoidf_(float z) {
    return 1.0f / (1.0f + __expf(-z));
}

// ---------------------------------------------------------------------------
// K1: one full pass over x.
//  - per-pixel spatial logit accumulated in registers (thread = 1 float2).
//  - per-(b,c) sum over HW via wave-PRIVATE LDS transpose tile. The tile is
//    per-wave, so no __syncthreads is needed around it: intra-wave
//    ds_write -> ds_read ordering is enforced by compiler lgkmcnt waits.
//    8-deep register prefetch keeps global loads in flight across the
//    transpose phase. Only 2 barriers per block (chansum init / final).
// grid (98, B), block 256 (4 waves). LDS 34.3 KB -> 4 blocks/CU.
// ---------------------------------------------------------------------------
__global__ __launch_bounds__(256) void k1_spatial_avg(
    const float* __restrict__ x, const float* __restrict__ sw,
    const float* __restrict__ sb, float* __restrict__ spatial_sig,
    float* __restrict__ avgsum)
{
    __shared__ float tile[4][32][65];   // per-wave transpose tile, padded
    __shared__ float chansum[CC];
    const int tid  = threadIdx.x;
    const int wave = tid >> 6;
    const int lane = tid & 63;
    const int cl   = lane & 31;
    const int seg  = lane >> 5;
    const int b    = blockIdx.y;
    const int p2   = blockIdx.x * 256 + tid;       // float2 index in [0, HW/2)
    const float2* xp = (const float2*)(x + (size_t)b * CC * HWSZ) + p2;

    chansum[tid] = 0.f;
    __syncthreads();

    float2 v[8], vn[8];
    #pragma unroll
    for (int u = 0; u < 8; ++u) v[u] = xp[(size_t)u * HW2];

    float s0 = 0.f, s1 = 0.f;
    #pragma unroll 4
    for (int g = 0; g < 32; ++g) {                 // 32 groups of 8 channels
        // prefetch next group while consuming this one
        if (g < 31) {
            #pragma unroll
            for (int u = 0; u < 8; ++u)
                vn[u] = xp[(size_t)((g + 1) * 8 + u) * HW2];
        }
        #pragma unroll
        for (int u = 0; u < 8; ++u) {
            const float w = sw[g * 8 + u];         // uniform -> scalar load
            s0 = fmaf(v[u].x, w, s0);
            s1 = fmaf(v[u].y, w, s1);
            tile[wave][(g & 3) * 8 + u][lane] = v[u].x + v[u].y;
        }
        if ((g & 3) == 3) {
            // wave-local transposed read: lane -> channel (2-way alias = free)
            float part = 0.f;
            #pragma unroll
            for (int j = 0; j < 32; ++j)
                part += tile[wave][cl][seg * 32 + j];
            part += __shfl_xor(part, 32, 64);      // combine seg 0/1
            if (lane < 32)
                atomicAdd(&chansum[(g >> 2) * 32 + cl], part);   // LDS atomic
        }
        #pragma unroll
        for (int u = 0; u < 8; ++u) v[u] = vn[u];
    }

    const float bias = sb[0];
    float2 o;
    o.x = sigmoidf_(s0 + bias);
    o.y = sigmoidf_(s1 + bias);
    ((float2*)(spatial_sig + (size_t)b * HWSZ))[p2] = o;

    __syncthreads();
    // one coalesced global atomic per channel per block
    atomicAdd(&avgsum[b * CC + tid], chansum[tid]);
}

// ---------------------------------------------------------------------------
// K2: channel MLP. grid (B), block 64. (unchanged — negligible cost)
// ---------------------------------------------------------------------------
__global__ __launch_bounds__(64) void k2_channel(
    const float* __restrict__ avgsum, const float* __restrict__ w1,
    const float* __restrict__ b1, const float* __restrict__ w2,
    const float* __restrict__ b2, float* __restrict__ channel_sig)
{
    __shared__ float avg[CC];
    __shared__ float hsh[C4];
    const int b = blockIdx.x;
    const int t = threadIdx.x;
    const float inv = 1.0f / (float)HWSZ;
    for (int c = t; c < CC; c += 64) avg[c] = avgsum[b * CC + c] * inv;
    __syncthreads();

    float acc = b1[t];
    const float* wrow = w1 + t * CC;     // cc1_w is (64, 256) row-major
    #pragma unroll 4
    for (int c = 0; c < CC; ++c) acc = fmaf(avg[c], wrow[c], acc);
    hsh[t] = fmaxf(acc, 0.f);
    __syncthreads();

    for (int c = t; c < CC; c += 64) {
        float a = b2[c];
        const float* w2r = w2 + c * C4;  // cc2_w is (256, 64) row-major
        #pragma unroll
        for (int o = 0; o < C4; ++o) a = fmaf(hsh[o], w2r[o], a);
        channel_sig[b * CC + c] = sigmoidf_(a);
    }
}

// ---------------------------------------------------------------------------
// K3: rolling-register row stencil. One wave streams a 28-row strip of one
// (b,c) plane; lane q owns float4 column q (q<56). Per row: 1 x load +
// 1 spatial load + 1 store; horizontal halos via 2 in-wave shuffles;
// vertical reuse in registers. x loads and out stores are NONTEMPORAL so
// the streaming traffic does not evict spatial_sig (1.6 MB/b, re-read by
// 256 c-planes) from L2.
// grid (2, B*C), block (64, 4).
// ---------------------------------------------------------------------------
__device__ __forceinline__ f4 ldnt(const float* p) {
    return __builtin_nontemporal_load((const f4*)p);
}

__device__ __forceinline__ f4 horiz4(f4 v, int q) {
    float l  = __shfl(v.w, q - 1, 64);
    float rr = __shfl(v.x, q + 1, 64);
    l  = (q == 0)  ? 0.f : l;    // zero padding at col -1
    rr = (q == 55) ? 0.f : rr;   // zero padding at col 224
    f4 h;
    h.x = l   + v.x + v.y;
    h.y = v.x + v.y + v.z;
    h.z = v.y + v.z + v.w;
    h.w = v.z + v.w + rr;
    return h;
}

__global__ __launch_bounds__(256) void k3_out(
    const float* __restrict__ x, const float* __restrict__ spatial_sig,
    const float* __restrict__ channel_sig, float* __restrict__ out)
{
    const int bc = blockIdx.y;               // b*C + c
    const int b  = bc >> 8;
    const int strip = blockIdx.x * 4 + threadIdx.y;  // 0..7, 28 rows each
    const int q  = threadIdx.x;              // lane = float4 column
    if (q >= 56) return;                     // 224/4 = 56 columns
    const int r0   = strip * 28;
    const int col0 = q * 4;

    const float* plane    = x           + (size_t)bc * HWSZ;
    const float* sp_plane = spatial_sig + (size_t)b  * HWSZ;
    float*       o_plane  = out         + (size_t)bc * HWSZ;
    const float  ch = channel_sig[bc];

    const f4 z4 = {0.f, 0.f, 0.f, 0.f};
    // prime the pipeline: rows r0-1 .. r0+2  (r0+2 <= 198 < 224 always)
    f4 vm = (r0 > 0) ? ldnt(plane + (r0 - 1) * WW + col0) : z4;
    f4 vc = ldnt(plane + (r0    ) * WW + col0);
    f4 vp = ldnt(plane + (r0 + 1) * WW + col0);
    f4 vn = ldnt(plane + (r0 + 2) * WW + col0);
    f4 sp = *(const f4*)(sp_plane + r0 * WW + col0);   // cached (reused)

    f4 hs_m = horiz4(vm, q);
    f4 hs_c = horiz4(vc, q);

    #pragma unroll 4
    for (int r = r0; r < r0 + 28; ++r) {
        // prefetch x row r+3 (2 iterations ahead of use)
        f4 vq = (r + 3 < HH) ? ldnt(plane + (r + 3) * WW + col0) : z4;
        // prefetch spatial row r+1 (1 iteration ahead), cached path
        f4 sp_n = (r + 1 < HH) ? *(const f4*)(sp_plane + (r + 1) * WW + col0) : z4;
        f4 hs_p = horiz4(vp, q);

        f4 o;
        o.x = vc.x * sp.x * ch * sigmoidf_(9.f * vc.x - (hs_m.x + hs_c.x + hs_p.x));
        o.y = vc.y * sp.y * ch * sigmoidf_(9.f * vc.y - (hs_m.y + hs_c.y + hs_p.y));
        o.z = vc.z * sp.z * ch * sigmoidf_(9.f * vc.z - (hs_m.z + hs_c.z + hs_p.z));
        o.w = vc.w * sp.w * ch * sigmoidf_(9.f * vc.w - (hs_m.w + hs_c.w + hs_p.w));
        __builtin_nontemporal_store(o, (f4*)(o_plane + r * WW + col0));

        vc = vp; vp = vn; vn = vq;
        hs_m = hs_c; hs_c = hs_p;
        sp = sp_n;
    }
}

// ---------------------------------------------------------------------------
extern "C" void kernel_launch(void* const* d_in, const int* in_sizes, int n_in,
                              void* d_out, int out_size, void* d_ws, size_t ws_size,
                              hipStream_t stream) {
    const float* x  = (const float*)d_in[0];
    const float* sw = (const float*)d_in[1];
    const float* sb = (const float*)d_in[2];
    const float* w1 = (const float*)d_in[3];
    const float* b1 = (const float*)d_in[4];
    const float* w2 = (const float*)d_in[5];
    const float* b2 = (const float*)d_in[6];
    float* out = (float*)d_out;

    float* spatial_sig = (float*)d_ws;                       // B*HW floats
    float* avgsum      = spatial_sig + (size_t)BB * HWSZ;    // B*C floats
    float* channel_sig = avgsum + BB * CC;                   // B*C floats

    hipMemsetAsync(avgsum, 0, BB * CC * sizeof(float), stream);

    k1_spatial_avg<<<dim3(HWSZ / 512, BB), 256, 0, stream>>>(
        x, sw, sb, spatial_sig, avgsum);
    k2_channel<<<dim3(BB), 64, 0, stream>>>(
        avgsum, w1, b1, w2, b2, channel_sig);
    k3_out<<<dim3(2, BB * CC), dim3(64, 4), 0, stream>>>(
        x, spatial_sig, channel_sig, out);
}